// Round 6
// baseline (320.473 us; speedup 1.0000x reference)
//
#include <hip/hip_runtime.h>
#include <math.h>

// B=4, T=2048, D=1024, H=16, HD=64
#define B_  4
#define T_  2048
#define D_  1024
#define H_  16
#define HD_ 64

typedef unsigned short ushort_t;
typedef unsigned int uint_t;
typedef __attribute__((ext_vector_type(8))) short bf16x8;
typedef __attribute__((ext_vector_type(4))) float f32x4;

// 0.125 * log2(e): folds 1/sqrt(HD) and exp->exp2.
#define SC_LOG2 0.1803368801111243f

__device__ inline ushort_t f2bf(float f) {           // RNE
  uint_t u = __float_as_uint(f);
  u += 0x7fffu + ((u >> 16) & 1u);
  return (ushort_t)(u >> 16);
}
__device__ inline ushort_t f2bf_fast(float f) {      // round-half-away
  return (ushort_t)((__float_as_uint(f) + 0x8000u) >> 16);
}
// RNE pack of two f32 into (lo16=a, hi16=b) bf16 pair — 1 VALU op vs 5.
__device__ inline uint_t cvtpk_bf16(float lo, float hi) {
  uint_t r;
  asm("v_cvt_pk_bf16_f32 %0, %1, %2" : "=v"(r) : "v"(lo), "v"(hi));
  return r;
}

__device__ inline void gload_lds16(const ushort_t* g, ushort_t* l) {
  __builtin_amdgcn_global_load_lds(
      (const __attribute__((address_space(1))) unsigned int*)g,
      (__attribute__((address_space(3))) unsigned int*)l, 16, 0, 0);
}

// ---------------------------------------------------------------------------
__global__ __launch_bounds__(256) void cvt_bf16(const float* __restrict__ in,
                                                ushort_t* __restrict__ out, int n) {
  int i = (blockIdx.x * 256 + threadIdx.x) * 4;
  if (i + 3 < n) {
    float4 v = *(const float4*)(in + i);
    uint_t lo = (uint_t)f2bf(v.x) | ((uint_t)f2bf(v.y) << 16);
    uint_t hi = (uint_t)f2bf(v.z) | ((uint_t)f2bf(v.w) << 16);
    *(uint2*)(out + i) = make_uint2(lo, hi);
  }
}

// per-key bias in log2 domain: masked ? -1e30 : log2(clip(engagement,1e-6))
__global__ __launch_bounds__(256) void bias_prep(const float* __restrict__ eng,
                                                 const int* __restrict__ mask,
                                                 float* __restrict__ biasA, int n) {
  int i = blockIdx.x * 256 + threadIdx.x;
  if (i < n) biasA[i] = mask[i] ? -1e30f : __log2f(fmaxf(eng[i], 1e-6f));
}

// ---------------------------------------------------------------------------
// C[M,N] = A[M,K] @ B[N,K]^T + bias[N], M=8192, K=1024 fixed.
// R6 == R5 with ONE fix: the epilogue per-wave patch pointer was
// `lds + w*10240` — ushort ELEMENTS, i.e. 20480 B stride; waves 6-7 ran off
// the 128 KiB LDS allocation (bytes-vs-elements slip -> OOB ds_write ->
// dropped/wrapped writes -> absmax 0.179). Patch is 64x80=5120 ushorts;
// correct stride is w*5120 (8*5120 = 40960 <= 65536).
//
// Structure (unchanged): 256^2-tile deep-pipelined GEMM (T1+T2+T3+T4+T5):
//  - 512 threads = 8 waves (2M x 4N); per-wave C block 128x64: acc[8][4].
//  - LDS = ring of 4 k-chunk slots; slot = A[256][32] + B[256][32] = 32 KB;
//    total 128 KiB, 1 block/CU. XOR-swizzled via pre-swizzled global source.
//  - Phase c: 12x ds_read_b128 | stage chunk c+3 (4x global_load_lds) |
//    setprio(1) 32 MFMA setprio(0) | s_waitcnt vmcnt(8) | raw s_barrier.
//    vmcnt never drains to 0 until the tail (8 -> 4 -> 0).
//  - Slot overwrite safe: stage into slot s issued only after the barrier
//    that postdates all (lgkm-drained) reads of s.
//  - XCD-aware block swizzle (grid % 8 == 0 for both call sites).
// ---------------------------------------------------------------------------
#define CHUNKS_ 32  // K=1024 / 32

#define STAGE_CHUNK(CK, SLOT)                                                  \
  {                                                                            \
    const int ck_ = (CK);                                                      \
    ushort_t* la_ = lds + (SLOT) * 16384 + wA * 32;                            \
    _Pragma("unroll")                                                          \
    for (int u = 0; u < 2; ++u) {                                              \
      gload_lds16(Ag + (size_t)u * 16384 + ck_ * 32, la_ + u * 512);           \
      gload_lds16(Bg + (size_t)u * 16384 + ck_ * 32, la_ + 8192 + u * 512);    \
    }                                                                          \
  }

template <int WRITE_BF16>
__global__ __launch_bounds__(512, 2) void gemm256(
    const ushort_t* __restrict__ A, const ushort_t* __restrict__ Bm,
    const float* __restrict__ bias, void* __restrict__ Cout,
    int N, int nbx) {
  __shared__ __align__(16) ushort_t lds[65536];  // 128 KiB

  const int tid = threadIdx.x;
  const int w = tid >> 6, lane = tid & 63;
  const int l15 = lane & 15, quad = lane >> 4;
  const int wr = w >> 2, wc = w & 3;

  // XCD-aware swizzle: hardware id -> tile id (bijective, grid % 8 == 0)
  int wg = blockIdx.x;
  const int cpx = gridDim.x >> 3;
  wg = (wg & 7) * cpx + (wg >> 3);
  const int m0 = (wg / nbx) * 256, n0 = (wg % nbx) * 256;

  // staging: pre-swizzled global source, linear LDS dest (16 rows/wave-instr)
  const int gc = (lane & 3) ^ ((lane >> 3) & 3);
  const ushort_t* Ag = A + (size_t)(m0 + w * 32 + (lane >> 2)) * 1024 + gc * 8;
  const ushort_t* Bg = Bm + (size_t)(n0 + w * 32 + (lane >> 2)) * 1024 + gc * 8;
  const int wA = w * 32;

  // frag-read offsets (swizzle-matched): p = quad ^ ((row>>1)&3)
  const int p8 = (quad ^ ((l15 >> 1) & 3)) * 8;
  const int rowA = (wr * 128 + l15) * 32 + p8;
  const int rowB = 8192 + (wc * 64 + l15) * 32 + p8;

  f32x4 acc[8][4];
#pragma unroll
  for (int mb = 0; mb < 8; ++mb)
#pragma unroll
    for (int nb = 0; nb < 4; ++nb) acc[mb][nb] = (f32x4){0.f, 0.f, 0.f, 0.f};

  // prologue: stage chunks 0,1,2; wait until chunk 0 landed (8 outstanding)
  STAGE_CHUNK(0, 0);
  STAGE_CHUNK(1, 1);
  STAGE_CHUNK(2, 2);
  asm volatile("s_waitcnt vmcnt(8)" ::: "memory");
  __builtin_amdgcn_s_barrier();
  __builtin_amdgcn_sched_barrier(0);

#pragma unroll 1
  for (int ph = 0; ph < CHUNKS_; ++ph) {
    const ushort_t* Ls = lds + (ph & 3) * 16384;
    bf16x8 af[8], bf[4];
#pragma unroll
    for (int mb = 0; mb < 8; ++mb)
      af[mb] = *(const bf16x8*)(Ls + rowA + mb * 512);
#pragma unroll
    for (int nb = 0; nb < 4; ++nb)
      bf[nb] = *(const bf16x8*)(Ls + rowB + nb * 512);
    if (ph < CHUNKS_ - 3) {
      STAGE_CHUNK(ph + 3, (ph + 3) & 3);
    }
    __builtin_amdgcn_s_setprio(1);
#pragma unroll
    for (int mb = 0; mb < 8; ++mb)
#pragma unroll
      for (int nb = 0; nb < 4; ++nb)
        acc[mb][nb] = __builtin_amdgcn_mfma_f32_16x16x32_bf16(
            af[mb], bf[nb], acc[mb][nb], 0, 0, 0);
    __builtin_amdgcn_s_setprio(0);
    // counted drain: chunk ph+1 must have landed after the barrier.
    if (ph < CHUNKS_ - 3)
      asm volatile("s_waitcnt vmcnt(8)" ::: "memory");
    else if (ph == CHUNKS_ - 3)
      asm volatile("s_waitcnt vmcnt(4)" ::: "memory");
    else
      asm volatile("s_waitcnt vmcnt(0)" ::: "memory");
    __builtin_amdgcn_s_barrier();
    __builtin_amdgcn_sched_barrier(0);
  }

  float bb[4];
#pragma unroll
  for (int nb = 0; nb < 4; ++nb) bb[nb] = bias[n0 + wc * 64 + nb * 16 + l15];

  if (WRITE_BF16) {
    // per-wave LDS patch (reuses slab memory; all slab reads drained above).
    // [64 rows][80 ushort]: 5120 ushorts per wave (FIX: was w*10240 -> OOB).
    ushort_t* patch = lds + w * 5120;
    ushort_t* Cb = (ushort_t*)Cout;
#pragma unroll
    for (int half = 0; half < 2; ++half) {
#pragma unroll
      for (int mb4 = 0; mb4 < 4; ++mb4) {
#pragma unroll
        for (int nb = 0; nb < 4; ++nb)
#pragma unroll
          for (int i = 0; i < 4; ++i)
            patch[(mb4 * 16 + quad * 4 + i) * 80 + nb * 16 + l15] =
                f2bf_fast(acc[half * 4 + mb4][nb][i] + bb[nb]);
      }
      // same-wave LDS write->read: ordered by lgkmcnt, no barrier needed.
#pragma unroll
      for (int it = 0; it < 8; ++it) {
        int rl = it * 8 + (lane >> 3);
        size_t grow = (size_t)(m0 + wr * 128 + half * 64 + rl);
        uint4 v = *(const uint4*)&patch[rl * 80 + (lane & 7) * 8];
        *(uint4*)&Cb[grow * N + n0 + wc * 64 + (lane & 7) * 8] = v;
      }
    }
  } else {
    float* Cf = (float*)Cout;
#pragma unroll
    for (int mb = 0; mb < 8; ++mb)
#pragma unroll
      for (int i = 0; i < 4; ++i) {
        size_t row = (size_t)(m0 + wr * 128 + mb * 16 + quad * 4 + i);
#pragma unroll
        for (int nb = 0; nb < 4; ++nb)
          Cf[row * N + n0 + wc * 64 + nb * 16 + l15] = acc[mb][nb][i] + bb[nb];
      }
  }
}

// ---------------------------------------------------------------------------
// MFMA flash attention, S^T formulation, software-pipelined (unchanged R3/R4).
// LDS (34048 B, 4 blocks/CU):
//   Kb0 @0 (8192) | Kb1 @8192 (8192) | Vb0 @16384 (8320) | Vb1 @24704 (8320)
//   bsh0 @33024 (256) | bsh1 @33280 (256) | lsum @33536 (512)
//   Ost @0 (18432) — epilogue only, aliases Kb/Vb (safe after final barrier)
// ---------------------------------------------------------------------------
#define ATTN_TILE(K0, Kc, Vc, bc, Kn, Vn, bn, PF)                              \
  {                                                                            \
    uint4 va_, vc_;                                                            \
    const bool pf_ = (PF);                                                     \
    if (pf_) {                                                                 \
      const int k1_ = (K0) + 64;                                               \
      _Pragma("unroll")                                                        \
      for (int u = 0; u < 2; ++u)                                              \
        gload_lds16(kbase + (size_t)(k1_ + w * 16 + u * 8 + kr) * rs + kgc * 8,\
                    &(Kn)[(w * 16 + u * 8) * 64]);                             \
      const ushort_t* vp_ = vbase + (size_t)(k1_ + 2 * kp) * rs + cc * 8;      \
      va_ = *(const uint4*)vp_;                                                \
      vc_ = *(const uint4*)(vp_ + rs);                                         \
      if (tid < 64) (bn)[tid] = bptr[k1_ + tid];                               \
    }                                                                          \
    bf16x8 kf0[4], kf1[4];                                                     \
    _Pragma("unroll")                                                          \
    for (int nb = 0; nb < 4; ++nb) {                                           \
      int key = nb * 16 + l15;                                                 \
      int p0 = (quad ^ (key & 7)) * 8;                                         \
      kf0[nb] = *(const bf16x8*)(&(Kc)[key * 64 + p0]);                        \
      kf1[nb] = *(const bf16x8*)(&(Kc)[key * 64 + (p0 ^ 32)]);                 \
    }                                                                          \
    bf16x8 vf0[4], vf1[4];                                                     \
    _Pragma("unroll")                                                          \
    for (int nbd = 0; nbd < 4; ++nbd) {                                        \
      vf0[nbd] = *(const bf16x8*)(&(Vc)[quad * 520 + (nbd * 16 + l15) * 8]);   \
      vf1[nbd] =                                                               \
          *(const bf16x8*)(&(Vc)[(4 + quad) * 520 + (nbd * 16 + l15) * 8]);    \
    }                                                                          \
    _Pragma("unroll")                                                          \
    for (int qb = 0; qb < 2; ++qb) {                                           \
      f32x4 st[4];                                                             \
      __builtin_amdgcn_s_setprio(1);                                           \
      _Pragma("unroll")                                                        \
      for (int nb = 0; nb < 4; ++nb) {                                         \
        f32x4 s = (f32x4){0.f, 0.f, 0.f, 0.f};                                 \
        s = __builtin_amdgcn_mfma_f32_16x16x32_bf16(kf0[nb], qf[qb][0], s, 0,  \
                                                    0, 0);                     \
        s = __builtin_amdgcn_mfma_f32_16x16x32_bf16(kf1[nb], qf[qb][1], s, 0,  \
                                                    0, 0);                     \
        st[nb] = s;                                                            \
      }                                                                        \
      __builtin_amdgcn_s_setprio(0);                                           \
      float pp[4][4];                                                          \
      float racc = 0.f;                                                        \
      _Pragma("unroll")                                                        \
      for (int nb = 0; nb < 4; ++nb) {                                         \
        f32x4 bv = *(const f32x4*)&(bc)[nb * 16 + quad * 4];                   \
        _Pragma("unroll")                                                      \
        for (int i = 0; i < 4; ++i) {                                          \
          float p = __builtin_amdgcn_exp2f(st[nb][i] * SC_LOG2 + bv[i]);       \
          pp[nb][i] = p;                                                       \
          racc += p;                                                           \
        }                                                                      \
      }                                                                        \
      rsum[qb] += racc;                                                        \
      union { uint4 u; bf16x8 v; } pf0, pf1;                                   \
      pf0.u.x = cvtpk_bf16(pp[0][0], pp[0][1]);                                \
      pf0.u.y = cvtpk_bf16(pp[0][2], pp[0][3]);                                \
      pf0.u.z = cvtpk_bf16(pp[1][0], pp[1][1]);                                \
      pf0.u.w = cvtpk_bf16(pp[1][2], pp[1][3]);                                \
      pf1.u.x = cvtpk_bf16(pp[2][0], pp[2][1]);                                \
      pf1.u.y = cvtpk_bf16(pp[2][2], pp[2][3]);                                \
      pf1.u.z = cvtpk_bf16(pp[3][0], pp[3][1]);                                \
      pf1.u.w = cvtpk_bf16(pp[3][2], pp[3][3]);                                \
      __builtin_amdgcn_s_setprio(1);                                           \
      _Pragma("unroll")                                                        \
      for (int nbd = 0; nbd < 4; ++nbd) {                                      \
        Oa[qb][nbd] = __builtin_amdgcn_mfma_f32_16x16x32_bf16(                 \
            pf0.v, vf0[nbd], Oa[qb][nbd], 0, 0, 0);                            \
        Oa[qb][nbd] = __builtin_amdgcn_mfma_f32_16x16x32_bf16(                 \
            pf1.v, vf1[nbd], Oa[qb][nbd], 0, 0, 0);                            \
      }                                                                        \
      __builtin_amdgcn_s_setprio(0);                                           \
    }                                                                          \
    if (pf_) {                                                                 \
      uint_t* dst_ = (uint_t*)&(Vn)[gp * 520 + cc * 64 + j0];                  \
      dst_[0]  = (va_.x & 0xffffu) | (vc_.x << 16);                            \
      dst_[4]  = (va_.x >> 16)     | (vc_.x & 0xffff0000u);                    \
      dst_[8]  = (va_.y & 0xffffu) | (vc_.y << 16);                            \
      dst_[12] = (va_.y >> 16)     | (vc_.y & 0xffff0000u);                    \
      dst_[16] = (va_.z & 0xffffu) | (vc_.z << 16);                            \
      dst_[20] = (va_.z >> 16)     | (vc_.z & 0xffff0000u);                    \
      dst_[24] = (va_.w & 0xffffu) | (vc_.w << 16);                            \
      dst_[28] = (va_.w >> 16)     | (vc_.w & 0xffff0000u);                    \
    }                                                                          \
    __syncthreads();                                                           \
  }

__global__ __launch_bounds__(256) void attn_mfma(
    const ushort_t* __restrict__ qkv, const float* __restrict__ biasA,
    ushort_t* __restrict__ oat) {
  __shared__ __align__(16) char smem[34048];
  ushort_t* Kb0 = (ushort_t*)(smem);
  ushort_t* Kb1 = (ushort_t*)(smem + 8192);
  ushort_t* Vb0 = (ushort_t*)(smem + 16384);
  ushort_t* Vb1 = (ushort_t*)(smem + 24704);
  float* bsh0 = (float*)(smem + 33024);
  float* bsh1 = (float*)(smem + 33280);
  float (*lsum)[32] = (float (*)[32])(smem + 33536);

  const int b = blockIdx.z, h = blockIdx.y;
  const int q0 = blockIdx.x * 128;
  const int tid = threadIdx.x;
  const int w = tid >> 6, lane = tid & 63;
  const int l15 = lane & 15, quad = lane >> 4;
  const size_t rs = 3 * D_;

  // Q B-frags (n=l15=q, k=quad*8+j=d) for the wave's 2 q-blocks.
  bf16x8 qf[2][2];
#pragma unroll
  for (int qb = 0; qb < 2; ++qb) {
    const ushort_t* qp =
        qkv + (size_t)(b * T_ + q0 + w * 32 + qb * 16 + l15) * rs + h * HD_;
    qf[qb][0] = *(const bf16x8*)(qp + quad * 8);
    qf[qb][1] = *(const bf16x8*)(qp + 32 + quad * 8);
  }

  f32x4 Oa[2][4];
#pragma unroll
  for (int qb = 0; qb < 2; ++qb)
#pragma unroll
    for (int nb = 0; nb < 4; ++nb) Oa[qb][nb] = (f32x4){0.f, 0.f, 0.f, 0.f};
  float rsum[2] = {0.f, 0.f};

  const ushort_t* kbase = qkv + (size_t)(b * T_) * rs + D_ + h * HD_;
  const ushort_t* vbase = kbase + D_;
  const float* bptr = biasA + b * T_;

  const int kr = lane >> 3, kc = lane & 7;
  const int kgc = kc ^ kr;
  const int kp = tid & 31, cc = tid >> 5;
  const int gp = (kp >> 4) * 4 + ((kp >> 1) & 3);
  const int j0 = ((kp >> 3) & 1) * 4 + 2 * (kp & 1);

  // ---- prologue: stage tile 0 into buf0
  {
#pragma unroll
    for (int u = 0; u < 2; ++u)
      gload_lds16(kbase + (size_t)(w * 16 + u * 8 + kr) * rs + kgc * 8,
                  &Kb0[(w * 16 + u * 8) * 64]);
    const ushort_t* vp = vbase + (size_t)(2 * kp) * rs + cc * 8;
    uint4 va = *(const uint4*)vp;
    uint4 vc = *(const uint4*)(vp + rs);
    if (tid < 64) bsh0[tid] = bptr[tid];
    uint_t* dst = (uint_t*)&Vb0[gp * 520 + cc * 64 + j0];
    dst[0]  = (va.x & 0xffffu) | (vc.x << 16);
    dst[4]  = (va.x >> 16)     | (vc.x & 0xffff0000u);
    dst[8]  = (va.y & 0xffffu) | (vc.y << 16);
    dst[12] = (va.y >> 16)     | (vc.y & 0xffff0000u);
    dst[16] = (va.z & 0xffffu) | (vc.z << 16);
    dst[20] = (va.z >> 16)     | (vc.z & 0xffff0000u);
    dst[24] = (va.w & 0xffffu) | (vc.w << 16);
    dst[28] = (va.w >> 16)     | (vc.w & 0xffff0000u);
  }
  __syncthreads();

  for (int k0 = 0; k0 < T_; k0 += 128) {
    ATTN_TILE(k0,      Kb0, Vb0, bsh0, Kb1, Vb1, bsh1, true);
    ATTN_TILE(k0 + 64, Kb1, Vb1, bsh1, Kb0, Vb0, bsh0, k0 + 128 < T_);
  }

  // ---- epilogue: rsum lives at q=l15; redistribute via per-wave LDS.
#pragma unroll
  for (int qb = 0; qb < 2; ++qb) {
    float r = rsum[qb];
    r += __shfl_xor(r, 16, 64);
    r += __shfl_xor(r, 32, 64);
    if (lane < 16) lsum[w][qb * 16 + lane] = r;
  }
  // Ost aliases Kb/Vb — safe: final tile ended with __syncthreads().
  ushort_t* OstW = (ushort_t*)(smem) + w * (32 * 72);
  // same-wave LDS write->read: ordered by lgkmcnt, no barrier needed.
#pragma unroll
  for (int qb = 0; qb < 2; ++qb) {
    f32x4 lr = *(const f32x4*)&lsum[w][qb * 16 + quad * 4];
    f32x4 invl;
#pragma unroll
    for (int i = 0; i < 4; ++i) invl[i] = __builtin_amdgcn_rcpf(lr[i]);
#pragma unroll
    for (int nbd = 0; nbd < 4; ++nbd)
#pragma unroll
      for (int i = 0; i < 4; ++i)
        OstW[(qb * 16 + quad * 4 + i) * 72 + nbd * 16 + l15] =
            f2bf_fast(Oa[qb][nbd][i] * invl[i]);
  }
  ushort_t* dst = oat + (size_t)(b * T_ + q0 + w * 32) * D_ + h * HD_;
#pragma unroll
  for (int pp = 0; pp < 4; ++pp) {
    int row = pp * 8 + (lane >> 3), c = lane & 7;
    uint4 v = *(const uint4*)&OstW[row * 72 + c * 8];
    *(uint4*)&dst[(size_t)row * D_ + c * 8] = v;
  }
}

// ---------------------------------------------------------------------------
extern "C" void kernel_launch(void* const* d_in, const int* in_sizes, int n_in,
                              void* d_out, int out_size, void* d_ws, size_t ws_size,
                              hipStream_t stream) {
  const float* x     = (const float*)d_in[0];
  const float* eng   = (const float*)d_in[1];
  const int*   mask  = (const int*)d_in[2];
  const float* qkv_w = (const float*)d_in[3];
  const float* qkv_b = (const float*)d_in[4];
  const float* out_w = (const float*)d_in[5];
  const float* out_b = (const float*)d_in[6];
  float* out = (float*)d_out;

  const int M = B_ * T_;
  const size_t nx = (size_t)M * D_;
  const size_t nwq = (size_t)3 * D_ * D_;
  const size_t nwo = (size_t)D_ * D_;
  const size_t nqkv = (size_t)M * 3 * D_;

  char* p = (char*)d_ws;
  ushort_t* xb    = (ushort_t*)p;            p += nx * 2;
  ushort_t* wqkvb = (ushort_t*)p;            p += nwq * 2;
  ushort_t* woutb = (ushort_t*)p;            p += nwo * 2;
  ushort_t* qkvb  = (ushort_t*)p;            p += nqkv * 2;
  ushort_t* oatb  = (ushort_t*)p;            p += nx * 2;
  float*    biasA = (float*)p;               p += (size_t)M * 4;

  cvt_bf16<<<(int)(nx / 1024), 256, 0, stream>>>(x, xb, (int)nx);
  cvt_bf16<<<(int)(nwq / 1024), 256, 0, stream>>>(qkv_w, wqkvb, (int)nwq);
  cvt_bf16<<<(int)(nwo / 1024), 256, 0, stream>>>(out_w, woutb, (int)nwo);
  bias_prep<<<M / 256, 256, 0, stream>>>(eng, mask, biasA, M);

  // GEMM1: [8192,1024] @ [3072,1024]^T -> bf16 [8192,3072]; grid 12*32=384
  gemm256<1><<<384, 512, 0, stream>>>(xb, wqkvb, qkv_b, qkvb, 3 * D_, 12);
  attn_mfma<<<dim3(T_ / 128, H_, B_), 256, 0, stream>>>(qkvb, biasA, oatb);
  // GEMM2: [8192,1024] @ [1024,1024]^T -> f32 [8192,1024]; grid 4*32=128
  gemm256<0><<<128, 512, 0, stream>>>(oatb, woutb, out_b, out, D_, 4);
}

// Round 7
// 295.864 us; speedup vs baseline: 1.0832x; 1.0832x over previous
//
#include <hip/hip_runtime.h>
#include <math.h>

// B=4, T=2048, D=1024, H=16, HD=64
#define B_  4
#define T_  2048
#define D_  1024
#define H_  16
#define HD_ 64

typedef unsigned short ushort_t;
typedef unsigned int uint_t;
typedef __attribute__((ext_vector_type(8))) short bf16x8;
typedef __attribute__((ext_vector_type(4))) float f32x4;

// 0.125 * log2(e): folds 1/sqrt(HD) and exp->exp2.
#define SC_LOG2 0.1803368801111243f

__device__ inline ushort_t f2bf(float f) {           // RNE
  uint_t u = __float_as_uint(f);
  u += 0x7fffu + ((u >> 16) & 1u);
  return (ushort_t)(u >> 16);
}
__device__ inline ushort_t f2bf_fast(float f) {      // round-half-away
  return (ushort_t)((__float_as_uint(f) + 0x8000u) >> 16);
}
// RNE pack of two f32 into (lo16=a, hi16=b) bf16 pair — 1 VALU op vs 5.
__device__ inline uint_t cvtpk_bf16(float lo, float hi) {
  uint_t r;
  asm("v_cvt_pk_bf16_f32 %0, %1, %2" : "=v"(r) : "v"(lo), "v"(hi));
  return r;
}

__device__ inline void gload_lds16(const ushort_t* g, ushort_t* l) {
  __builtin_amdgcn_global_load_lds(
      (const __attribute__((address_space(1))) unsigned int*)g,
      (__attribute__((address_space(3))) unsigned int*)l, 16, 0, 0);
}

// ---------------------------------------------------------------------------
__global__ __launch_bounds__(256) void cvt_bf16(const float* __restrict__ in,
                                                ushort_t* __restrict__ out, int n) {
  int i = (blockIdx.x * 256 + threadIdx.x) * 4;
  if (i + 3 < n) {
    float4 v = *(const float4*)(in + i);
    uint_t lo = (uint_t)f2bf(v.x) | ((uint_t)f2bf(v.y) << 16);
    uint_t hi = (uint_t)f2bf(v.z) | ((uint_t)f2bf(v.w) << 16);
    *(uint2*)(out + i) = make_uint2(lo, hi);
  }
}

// per-key bias in log2 domain: masked ? -1e30 : log2(clip(engagement,1e-6))
__global__ __launch_bounds__(256) void bias_prep(const float* __restrict__ eng,
                                                 const int* __restrict__ mask,
                                                 float* __restrict__ biasA, int n) {
  int i = blockIdx.x * 256 + threadIdx.x;
  if (i < n) biasA[i] = mask[i] ? -1e30f : __log2f(fmaxf(eng[i], 1e-6f));
}

// ---------------------------------------------------------------------------
// C[M,N] = A[M,K] @ B[N,K]^T + bias[N], M=8192, K=1024 fixed.
// R7: counted-vmcnt pipeline kept, footprint shrunk for occupancy + balance.
// R6 was neutral because 128 KiB LDS -> 1 block/CU: GEMM1 384 blocks = 2
// rounds at 75%, GEMM2 128 blocks = half the GPU idle, and no co-resident
// block to absorb barrier stalls.
//  - Tile 128x256; 512 thr = 8 waves (2r x 4c); per-wave C 64x64: acc[4][4]
//    (~115 VGPR, capped 128 via __launch_bounds__(512,4)).
//  - LDS ring of THREE BK=32 slots; slot = A[128][32]+B[256][32] = 24 KB;
//    total 72 KiB -> 2 blocks/CU (16 waves) co-resident.
//  - Phase c: 8x ds_read_b128 | stage chunk c+2 (3x global_load_lds) |
//    setprio(1) 16 MFMA setprio(0) | vmcnt(3) (chunk c+1 landed; 3 loads/
//    chunk, 2 chunks in flight) | s_barrier. Tail drains to 0.
//  - Slot safety: slot (c+2)%3 last read in phase c-1; those ds_reads are
//    consumed by MFMAs (lgkm-drained) before phase c-1's barrier.
//  - Grids: GEMM1 64x12=768 (3/CU balanced), GEMM2 64x4=256 (exact). Both
//    %8==0 -> bijective XCD swizzle.
// ---------------------------------------------------------------------------
#define CHUNKS_ 32  // K=1024 / 32

#define STAGE_CHUNK(CK, SLOT)                                                  \
  {                                                                            \
    const int ck_ = (CK);                                                      \
    ushort_t* sb_ = lds + (SLOT) * 12288;                                      \
    gload_lds16(Ag + (size_t)ck_ * 32, sb_ + w * 512);                         \
    gload_lds16(Bg + (size_t)ck_ * 32, sb_ + 4096 + w * 1024);                 \
    gload_lds16(Bg + 16384 + (size_t)ck_ * 32, sb_ + 4096 + w * 1024 + 512);   \
  }

template <int WRITE_BF16>
__global__ __launch_bounds__(512, 4) void gemm256(
    const ushort_t* __restrict__ A, const ushort_t* __restrict__ Bm,
    const float* __restrict__ bias, void* __restrict__ Cout,
    int N, int nbx) {
  __shared__ __align__(16) ushort_t lds[36864];  // 72 KiB: 3 x 24 KB slots

  const int tid = threadIdx.x;
  const int w = tid >> 6, lane = tid & 63;
  const int l15 = lane & 15, quad = lane >> 4;
  const int wr = w >> 2, wc = w & 3;

  // XCD-aware swizzle: hardware id -> tile id (bijective, grid % 8 == 0)
  int wg = blockIdx.x;
  const int cpx = gridDim.x >> 3;
  wg = (wg & 7) * cpx + (wg >> 3);
  const int m0 = (wg / nbx) * 128, n0 = (wg % nbx) * 256;

  // staging: pre-swizzled global source, linear LDS dest.
  // wave stages A rows [w*16,w*16+16) and B rows [w*32,w*32+32).
  const int gc = (lane & 3) ^ ((lane >> 3) & 3);
  const ushort_t* Ag = A + (size_t)(m0 + w * 16 + (lane >> 2)) * 1024 + gc * 8;
  const ushort_t* Bg = Bm + (size_t)(n0 + w * 32 + (lane >> 2)) * 1024 + gc * 8;

  // frag-read offsets (swizzle-matched): p = quad ^ ((l15>>1)&3)
  const int p8 = (quad ^ ((l15 >> 1) & 3)) * 8;
  const int rowA = (wr * 64 + l15) * 32 + p8;          // A region at slot base
  const int rowB = 4096 + (wc * 64 + l15) * 32 + p8;   // B region at +8 KB

  f32x4 acc[4][4];
#pragma unroll
  for (int mb = 0; mb < 4; ++mb)
#pragma unroll
    for (int nb = 0; nb < 4; ++nb) acc[mb][nb] = (f32x4){0.f, 0.f, 0.f, 0.f};

  // prologue: stage chunks 0,1 into slots 0,1; wait chunk 0 (3 outstanding)
  STAGE_CHUNK(0, 0);
  STAGE_CHUNK(1, 1);
  asm volatile("s_waitcnt vmcnt(3)" ::: "memory");
  __builtin_amdgcn_s_barrier();
  __builtin_amdgcn_sched_barrier(0);

  int s_cur = 0;
#pragma unroll 1
  for (int ph = 0; ph < CHUNKS_; ++ph) {
    const ushort_t* Ls = lds + s_cur * 12288;
    bf16x8 af[4], bf[4];
#pragma unroll
    for (int mb = 0; mb < 4; ++mb)
      af[mb] = *(const bf16x8*)(Ls + rowA + mb * 512);
#pragma unroll
    for (int nb = 0; nb < 4; ++nb)
      bf[nb] = *(const bf16x8*)(Ls + rowB + nb * 512);
    if (ph < CHUNKS_ - 2) {
      const int s_n2 = (s_cur == 0) ? 2 : s_cur - 1;  // (s_cur+2)%3
      STAGE_CHUNK(ph + 2, s_n2);
    }
    __builtin_amdgcn_s_setprio(1);
#pragma unroll
    for (int mb = 0; mb < 4; ++mb)
#pragma unroll
      for (int nb = 0; nb < 4; ++nb)
        acc[mb][nb] = __builtin_amdgcn_mfma_f32_16x16x32_bf16(
            af[mb], bf[nb], acc[mb][nb], 0, 0, 0);
    __builtin_amdgcn_s_setprio(0);
    // counted drain: chunk ph+1 landed after this (never 0 until tail).
    if (ph < CHUNKS_ - 2)
      asm volatile("s_waitcnt vmcnt(3)" ::: "memory");
    else
      asm volatile("s_waitcnt vmcnt(0)" ::: "memory");
    __builtin_amdgcn_s_barrier();
    __builtin_amdgcn_sched_barrier(0);
    s_cur = (s_cur == 2) ? 0 : s_cur + 1;
  }

  float bb[4];
#pragma unroll
  for (int nb = 0; nb < 4; ++nb) bb[nb] = bias[n0 + wc * 64 + nb * 16 + l15];

  if (WRITE_BF16) {
    // per-wave LDS patch [64][72] ushorts = 4608/wave; 8*4608 = 36864 exact.
    ushort_t* patch = lds + w * 4608;
    ushort_t* Cb = (ushort_t*)Cout;
#pragma unroll
    for (int mb = 0; mb < 4; ++mb)
#pragma unroll
      for (int nb = 0; nb < 4; ++nb)
#pragma unroll
        for (int i = 0; i < 4; ++i)
          patch[(mb * 16 + quad * 4 + i) * 72 + nb * 16 + l15] =
              f2bf_fast(acc[mb][nb][i] + bb[nb]);
    // same-wave LDS write->read: ordered by lgkmcnt, no barrier needed.
#pragma unroll
    for (int it = 0; it < 8; ++it) {
      int rl = it * 8 + (lane >> 3);
      size_t grow = (size_t)(m0 + wr * 64 + rl);
      uint4 v = *(const uint4*)&patch[rl * 72 + (lane & 7) * 8];
      *(uint4*)&Cb[grow * N + n0 + wc * 64 + (lane & 7) * 8] = v;
    }
  } else {
    float* Cf = (float*)Cout;
#pragma unroll
    for (int mb = 0; mb < 4; ++mb)
#pragma unroll
      for (int i = 0; i < 4; ++i) {
        size_t row = (size_t)(m0 + wr * 64 + mb * 16 + quad * 4 + i);
#pragma unroll
        for (int nb = 0; nb < 4; ++nb)
          Cf[row * N + n0 + wc * 64 + nb * 16 + l15] = acc[mb][nb][i] + bb[nb];
      }
  }
}

// ---------------------------------------------------------------------------
// MFMA flash attention, S^T formulation, software-pipelined (unchanged R3/R4).
// LDS (34048 B, 4 blocks/CU):
//   Kb0 @0 (8192) | Kb1 @8192 (8192) | Vb0 @16384 (8320) | Vb1 @24704 (8320)
//   bsh0 @33024 (256) | bsh1 @33280 (256) | lsum @33536 (512)
//   Ost @0 (18432) — epilogue only, aliases Kb/Vb (safe after final barrier)
// ---------------------------------------------------------------------------
#define ATTN_TILE(K0, Kc, Vc, bc, Kn, Vn, bn, PF)                              \
  {                                                                            \
    uint4 va_, vc_;                                                            \
    const bool pf_ = (PF);                                                     \
    if (pf_) {                                                                 \
      const int k1_ = (K0) + 64;                                               \
      _Pragma("unroll")                                                        \
      for (int u = 0; u < 2; ++u)                                              \
        gload_lds16(kbase + (size_t)(k1_ + w * 16 + u * 8 + kr) * rs + kgc * 8,\
                    &(Kn)[(w * 16 + u * 8) * 64]);                             \
      const ushort_t* vp_ = vbase + (size_t)(k1_ + 2 * kp) * rs + cc * 8;      \
      va_ = *(const uint4*)vp_;                                                \
      vc_ = *(const uint4*)(vp_ + rs);                                         \
      if (tid < 64) (bn)[tid] = bptr[k1_ + tid];                               \
    }                                                                          \
    bf16x8 kf0[4], kf1[4];                                                     \
    _Pragma("unroll")                                                          \
    for (int nb = 0; nb < 4; ++nb) {                                           \
      int key = nb * 16 + l15;                                                 \
      int p0 = (quad ^ (key & 7)) * 8;                                         \
      kf0[nb] = *(const bf16x8*)(&(Kc)[key * 64 + p0]);                        \
      kf1[nb] = *(const bf16x8*)(&(Kc)[key * 64 + (p0 ^ 32)]);                 \
    }                                                                          \
    bf16x8 vf0[4], vf1[4];                                                     \
    _Pragma("unroll")                                                          \
    for (int nbd = 0; nbd < 4; ++nbd) {                                        \
      vf0[nbd] = *(const bf16x8*)(&(Vc)[quad * 520 + (nbd * 16 + l15) * 8]);   \
      vf1[nbd] =                                                               \
          *(const bf16x8*)(&(Vc)[(4 + quad) * 520 + (nbd * 16 + l15) * 8]);    \
    }                                                                          \
    _Pragma("unroll")                                                          \
    for (int qb = 0; qb < 2; ++qb) {                                           \
      f32x4 st[4];                                                             \
      __builtin_amdgcn_s_setprio(1);                                           \
      _Pragma("unroll")                                                        \
      for (int nb = 0; nb < 4; ++nb) {                                         \
        f32x4 s = (f32x4){0.f, 0.f, 0.f, 0.f};                                 \
        s = __builtin_amdgcn_mfma_f32_16x16x32_bf16(kf0[nb], qf[qb][0], s, 0,  \
                                                    0, 0);                     \
        s = __builtin_amdgcn_mfma_f32_16x16x32_bf16(kf1[nb], qf[qb][1], s, 0,  \
                                                    0, 0);                     \
        st[nb] = s;                                                            \
      }                                                                        \
      __builtin_amdgcn_s_setprio(0);                                           \
      float pp[4][4];                                                          \
      float racc = 0.f;                                                        \
      _Pragma("unroll")                                                        \
      for (int nb = 0; nb < 4; ++nb) {                                         \
        f32x4 bv = *(const f32x4*)&(bc)[nb * 16 + quad * 4];                   \
        _Pragma("unroll")                                                      \
        for (int i = 0; i < 4; ++i) {                                          \
          float p = __builtin_amdgcn_exp2f(st[nb][i] * SC_LOG2 + bv[i]);       \
          pp[nb][i] = p;                                                       \
          racc += p;                                                           \
        }                                                                      \
      }                                                                        \
      rsum[qb] += racc;                                                        \
      union { uint4 u; bf16x8 v; } pf0, pf1;                                   \
      pf0.u.x = cvtpk_bf16(pp[0][0], pp[0][1]);                                \
      pf0.u.y = cvtpk_bf16(pp[0][2], pp[0][3]);                                \
      pf0.u.z = cvtpk_bf16(pp[1][0], pp[1][1]);                                \
      pf0.u.w = cvtpk_bf16(pp[1][2], pp[1][3]);                                \
      pf1.u.x = cvtpk_bf16(pp[2][0], pp[2][1]);                                \
      pf1.u.y = cvtpk_bf16(pp[2][2], pp[2][3]);                                \
      pf1.u.z = cvtpk_bf16(pp[3][0], pp[3][1]);                                \
      pf1.u.w = cvtpk_bf16(pp[3][2], pp[3][3]);                                \
      __builtin_amdgcn_s_setprio(1);                                           \
      _Pragma("unroll")                                                        \
      for (int nbd = 0; nbd < 4; ++nbd) {                                      \
        Oa[qb][nbd] = __builtin_amdgcn_mfma_f32_16x16x32_bf16(                 \
            pf0.v, vf0[nbd], Oa[qb][nbd], 0, 0, 0);                            \
        Oa[qb][nbd] = __builtin_amdgcn_mfma_f32_16x16x32_bf16(                 \
            pf1.v, vf1[nbd], Oa[qb][nbd], 0, 0, 0);                            \
      }                                                                        \
      __builtin_amdgcn_s_setprio(0);                                           \
    }                                                                          \
    if (pf_) {                                                                 \
      uint_t* dst_ = (uint_t*)&(Vn)[gp * 520 + cc * 64 + j0];                  \
      dst_[0]  = (va_.x & 0xffffu) | (vc_.x << 16);                            \
      dst_[4]  = (va_.x >> 16)     | (vc_.x & 0xffff0000u);                    \
      dst_[8]  = (va_.y & 0xffffu) | (vc_.y << 16);                            \
      dst_[12] = (va_.y >> 16)     | (vc_.y & 0xffff0000u);                    \
      dst_[16] = (va_.z & 0xffffu) | (vc_.z << 16);                            \
      dst_[20] = (va_.z >> 16)     | (vc_.z & 0xffff0000u);                    \
      dst_[24] = (va_.w & 0xffffu) | (vc_.w << 16);                            \
      dst_[28] = (va_.w >> 16)     | (vc_.w & 0xffff0000u);                    \
    }                                                                          \
    __syncthreads();                                                           \
  }

__global__ __launch_bounds__(256) void attn_mfma(
    const ushort_t* __restrict__ qkv, const float* __restrict__ biasA,
    ushort_t* __restrict__ oat) {
  __shared__ __align__(16) char smem[34048];
  ushort_t* Kb0 = (ushort_t*)(smem);
  ushort_t* Kb1 = (ushort_t*)(smem + 8192);
  ushort_t* Vb0 = (ushort_t*)(smem + 16384);
  ushort_t* Vb1 = (ushort_t*)(smem + 24704);
  float* bsh0 = (float*)(smem + 33024);
  float* bsh1 = (float*)(smem + 33280);
  float (*lsum)[32] = (float (*)[32])(smem + 33536);

  const int b = blockIdx.z, h = blockIdx.y;
  const int q0 = blockIdx.x * 128;
  const int tid = threadIdx.x;
  const int w = tid >> 6, lane = tid & 63;
  const int l15 = lane & 15, quad = lane >> 4;
  const size_t rs = 3 * D_;

  // Q B-frags (n=l15=q, k=quad*8+j=d) for the wave's 2 q-blocks.
  bf16x8 qf[2][2];
#pragma unroll
  for (int qb = 0; qb < 2; ++qb) {
    const ushort_t* qp =
        qkv + (size_t)(b * T_ + q0 + w * 32 + qb * 16 + l15) * rs + h * HD_;
    qf[qb][0] = *(const bf16x8*)(qp + quad * 8);
    qf[qb][1] = *(const bf16x8*)(qp + 32 + quad * 8);
  }

  f32x4 Oa[2][4];
#pragma unroll
  for (int qb = 0; qb < 2; ++qb)
#pragma unroll
    for (int nb = 0; nb < 4; ++nb) Oa[qb][nb] = (f32x4){0.f, 0.f, 0.f, 0.f};
  float rsum[2] = {0.f, 0.f};

  const ushort_t* kbase = qkv + (size_t)(b * T_) * rs + D_ + h * HD_;
  const ushort_t* vbase = kbase + D_;
  const float* bptr = biasA + b * T_;

  const int kr = lane >> 3, kc = lane & 7;
  const int kgc = kc ^ kr;
  const int kp = tid & 31, cc = tid >> 5;
  const int gp = (kp >> 4) * 4 + ((kp >> 1) & 3);
  const int j0 = ((kp >> 3) & 1) * 4 + 2 * (kp & 1);

  // ---- prologue: stage tile 0 into buf0
  {
#pragma unroll
    for (int u = 0; u < 2; ++u)
      gload_lds16(kbase + (size_t)(w * 16 + u * 8 + kr) * rs + kgc * 8,
                  &Kb0[(w * 16 + u * 8) * 64]);
    const ushort_t* vp = vbase + (size_t)(2 * kp) * rs + cc * 8;
    uint4 va = *(const uint4*)vp;
    uint4 vc = *(const uint4*)(vp + rs);
    if (tid < 64) bsh0[tid] = bptr[tid];
    uint_t* dst = (uint_t*)&Vb0[gp * 520 + cc * 64 + j0];
    dst[0]  = (va.x & 0xffffu) | (vc.x << 16);
    dst[4]  = (va.x >> 16)     | (vc.x & 0xffff0000u);
    dst[8]  = (va.y & 0xffffu) | (vc.y << 16);
    dst[12] = (va.y >> 16)     | (vc.y & 0xffff0000u);
    dst[16] = (va.z & 0xffffu) | (vc.z << 16);
    dst[20] = (va.z >> 16)     | (vc.z & 0xffff0000u);
    dst[24] = (va.w & 0xffffu) | (vc.w << 16);
    dst[28] = (va.w >> 16)     | (vc.w & 0xffff0000u);
  }
  __syncthreads();

  for (int k0 = 0; k0 < T_; k0 += 128) {
    ATTN_TILE(k0,      Kb0, Vb0, bsh0, Kb1, Vb1, bsh1, true);
    ATTN_TILE(k0 + 64, Kb1, Vb1, bsh1, Kb0, Vb0, bsh0, k0 + 128 < T_);
  }

  // ---- epilogue: rsum lives at q=l15; redistribute via per-wave LDS.
#pragma unroll
  for (int qb = 0; qb < 2; ++qb) {
    float r = rsum[qb];
    r += __shfl_xor(r, 16, 64);
    r += __shfl_xor(r, 32, 64);
    if (lane < 16) lsum[w][qb * 16 + lane] = r;
  }
  // Ost aliases Kb/Vb — safe: final tile ended with __syncthreads().
  ushort_t* OstW = (ushort_t*)(smem) + w * (32 * 72);
  // same-wave LDS write->read: ordered by lgkmcnt, no barrier needed.
#pragma unroll
  for (int qb = 0; qb < 2; ++qb) {
    f32x4 lr = *(const f32x4*)&lsum[w][qb * 16 + quad * 4];
    f32x4 invl;
#pragma unroll
    for (int i = 0; i < 4; ++i) invl[i] = __builtin_amdgcn_rcpf(lr[i]);
#pragma unroll
    for (int nbd = 0; nbd < 4; ++nbd)
#pragma unroll
      for (int i = 0; i < 4; ++i)
        OstW[(qb * 16 + quad * 4 + i) * 72 + nbd * 16 + l15] =
            f2bf_fast(Oa[qb][nbd][i] * invl[i]);
  }
  ushort_t* dst = oat + (size_t)(b * T_ + q0 + w * 32) * D_ + h * HD_;
#pragma unroll
  for (int pp = 0; pp < 4; ++pp) {
    int row = pp * 8 + (lane >> 3), c = lane & 7;
    uint4 v = *(const uint4*)&OstW[row * 72 + c * 8];
    *(uint4*)&dst[(size_t)row * D_ + c * 8] = v;
  }
}

// ---------------------------------------------------------------------------
extern "C" void kernel_launch(void* const* d_in, const int* in_sizes, int n_in,
                              void* d_out, int out_size, void* d_ws, size_t ws_size,
                              hipStream_t stream) {
  const float* x     = (const float*)d_in[0];
  const float* eng   = (const float*)d_in[1];
  const int*   mask  = (const int*)d_in[2];
  const float* qkv_w = (const float*)d_in[3];
  const float* qkv_b = (const float*)d_in[4];
  const float* out_w = (const float*)d_in[5];
  const float* out_b = (const float*)d_in[6];
  float* out = (float*)d_out;

  const int M = B_ * T_;
  const size_t nx = (size_t)M * D_;
  const size_t nwq = (size_t)3 * D_ * D_;
  const size_t nwo = (size_t)D_ * D_;
  const size_t nqkv = (size_t)M * 3 * D_;

  char* p = (char*)d_ws;
  ushort_t* xb    = (ushort_t*)p;            p += nx * 2;
  ushort_t* wqkvb = (ushort_t*)p;            p += nwq * 2;
  ushort_t* woutb = (ushort_t*)p;            p += nwo * 2;
  ushort_t* qkvb  = (ushort_t*)p;            p += nqkv * 2;
  ushort_t* oatb  = (ushort_t*)p;            p += nx * 2;
  float*    biasA = (float*)p;               p += (size_t)M * 4;

  cvt_bf16<<<(int)(nx / 1024), 256, 0, stream>>>(x, xb, (int)nx);
  cvt_bf16<<<(int)(nwq / 1024), 256, 0, stream>>>(qkv_w, wqkvb, (int)nwq);
  cvt_bf16<<<(int)(nwo / 1024), 256, 0, stream>>>(out_w, woutb, (int)nwo);
  bias_prep<<<M / 256, 256, 0, stream>>>(eng, mask, biasA, M);

  // GEMM1: [8192,1024] @ [3072,1024]^T -> bf16 [8192,3072]; 64x12 = 768 blocks
  gemm256<1><<<768, 512, 0, stream>>>(xb, wqkvb, qkv_b, qkvb, 3 * D_, 12);
  attn_mfma<<<dim3(T_ / 128, H_, B_), 256, 0, stream>>>(qkvb, biasA, oatb);
  // GEMM2: [8192,1024] @ [1024,1024]^T -> f32 [8192,1024]; 64x4 = 256 blocks
  gemm256<0><<<256, 512, 0, stream>>>(oatb, woutb, out_b, out, D_, 4);
}

// Round 8
// 282.604 us; speedup vs baseline: 1.1340x; 1.0469x over previous
//
#include <hip/hip_runtime.h>
#include <math.h>

// B=4, T=2048, D=1024, H=16, HD=64
#define B_  4
#define T_  2048
#define D_  1024
#define H_  16
#define HD_ 64

typedef unsigned short ushort_t;
typedef unsigned int uint_t;
typedef __attribute__((ext_vector_type(8))) short bf16x8;
typedef __attribute__((ext_vector_type(4))) float f32x4;

// 0.125 * log2(e): folds 1/sqrt(HD) and exp->exp2.
#define SC_LOG2 0.1803368801111243f

__device__ inline ushort_t f2bf(float f) {           // RNE
  uint_t u = __float_as_uint(f);
  u += 0x7fffu + ((u >> 16) & 1u);
  return (ushort_t)(u >> 16);
}
__device__ inline ushort_t f2bf_fast(float f) {      // round-half-away
  return (ushort_t)((__float_as_uint(f) + 0x8000u) >> 16);
}
// RNE pack of two f32 into (lo16=a, hi16=b) bf16 pair — 1 VALU op vs 5.
__device__ inline uint_t cvtpk_bf16(float lo, float hi) {
  uint_t r;
  asm("v_cvt_pk_bf16_f32 %0, %1, %2" : "=v"(r) : "v"(lo), "v"(hi));
  return r;
}

__device__ inline void gload_lds16(const ushort_t* g, ushort_t* l) {
  __builtin_amdgcn_global_load_lds(
      (const __attribute__((address_space(1))) unsigned int*)g,
      (__attribute__((address_space(3))) unsigned int*)l, 16, 0, 0);
}

// ---------------------------------------------------------------------------
__global__ __launch_bounds__(256) void cvt_bf16(const float* __restrict__ in,
                                                ushort_t* __restrict__ out, int n) {
  int i = (blockIdx.x * 256 + threadIdx.x) * 4;
  if (i + 3 < n) {
    float4 v = *(const float4*)(in + i);
    uint_t lo = (uint_t)f2bf(v.x) | ((uint_t)f2bf(v.y) << 16);
    uint_t hi = (uint_t)f2bf(v.z) | ((uint_t)f2bf(v.w) << 16);
    *(uint2*)(out + i) = make_uint2(lo, hi);
  }
}

// per-key bias in log2 domain: masked ? -1e30 : log2(clip(engagement,1e-6))
__global__ __launch_bounds__(256) void bias_prep(const float* __restrict__ eng,
                                                 const int* __restrict__ mask,
                                                 float* __restrict__ biasA, int n) {
  int i = blockIdx.x * 256 + threadIdx.x;
  if (i < n) biasA[i] = mask[i] ? -1e30f : __log2f(fmaxf(eng[i], 1e-6f));
}

// ---------------------------------------------------------------------------
// C[M,N] = A[M,K] @ B[N,K]^T + bias[N], M=8192, K=1024 fixed.
// R8: R7's pipelined GEMM templated on BN (tile = 128 x BN).
//  BN=256 (GEMM1): identical codegen to R7 — 24 KB slot x3 = 72 KB, 2/CU.
//  BN=128 (GEMM2): 16 KB slot x3 = 48 KB -> grid 512 blocks = 2/CU resident
//    (R7's GEMM2 had 256 blocks = 1/CU = only 8 waves/CU of stall cover).
//  Per wave: acc[4][BN/64]; phase: ds_reads | stage c+2 | 8-16 MFMA |
//  counted vmcnt | s_barrier. Tail drains to 0.
// ---------------------------------------------------------------------------
#define CHUNKS_ 32  // K=1024 / 32

#define STAGE_CHUNK(CK, SLOT)                                                  \
  {                                                                            \
    const int ck_ = (CK);                                                      \
    ushort_t* sb_ = lds + (SLOT) * SLOT_E;                                     \
    gload_lds16(Ag + (size_t)ck_ * 32, sb_ + w * 512);                         \
    if constexpr (BN == 256) {                                                 \
      gload_lds16(Bg + (size_t)ck_ * 32, sb_ + 4096 + w * 1024);               \
      gload_lds16(Bg + 16384 + (size_t)ck_ * 32, sb_ + 4096 + w * 1024 + 512); \
    } else {                                                                   \
      gload_lds16(Bg + (size_t)ck_ * 32, sb_ + 4096 + w * 512);                \
    }                                                                          \
  }

template <int WRITE_BF16, int BN>
__global__ __launch_bounds__(512, 4) void gemm256(
    const ushort_t* __restrict__ A, const ushort_t* __restrict__ Bm,
    const float* __restrict__ bias, void* __restrict__ Cout,
    int N, int nbx) {
  constexpr int SLOT_E = 4096 + BN * 32;  // ushorts per ring slot
  constexpr int NBB = BN / 64;            // B col-blocks per wave
  constexpr int WCOLS = BN / 4;           // cols per wave-col group
  __shared__ __align__(16) ushort_t lds[3 * SLOT_E];

  const int tid = threadIdx.x;
  const int w = tid >> 6, lane = tid & 63;
  const int l15 = lane & 15, quad = lane >> 4;
  const int wr = w >> 2, wc = w & 3;

  // XCD-aware swizzle: hardware id -> tile id (bijective, grid % 8 == 0)
  int wg = blockIdx.x;
  const int cpx = gridDim.x >> 3;
  wg = (wg & 7) * cpx + (wg >> 3);
  const int m0 = (wg / nbx) * 128, n0 = (wg % nbx) * BN;

  // staging: pre-swizzled global source, linear LDS dest.
  const int gc = (lane & 3) ^ ((lane >> 3) & 3);
  const ushort_t* Ag = A + (size_t)(m0 + w * 16 + (lane >> 2)) * 1024 + gc * 8;
  const ushort_t* Bg =
      Bm + (size_t)(n0 + w * (BN / 8) + (lane >> 2)) * 1024 + gc * 8;

  // frag-read offsets (swizzle-matched): p = quad ^ ((l15>>1)&3)
  const int p8 = (quad ^ ((l15 >> 1) & 3)) * 8;
  const int rowA = (wr * 64 + l15) * 32 + p8;          // A region at slot base
  const int rowB = 4096 + (wc * WCOLS + l15) * 32 + p8;

  f32x4 acc[4][NBB];
#pragma unroll
  for (int mb = 0; mb < 4; ++mb)
#pragma unroll
    for (int nb = 0; nb < NBB; ++nb) acc[mb][nb] = (f32x4){0.f, 0.f, 0.f, 0.f};

  // prologue: stage chunks 0,1 into slots 0,1; wait chunk 0 landed.
  STAGE_CHUNK(0, 0);
  STAGE_CHUNK(1, 1);
  if constexpr (BN == 256)
    asm volatile("s_waitcnt vmcnt(3)" ::: "memory");
  else
    asm volatile("s_waitcnt vmcnt(2)" ::: "memory");
  __builtin_amdgcn_s_barrier();
  __builtin_amdgcn_sched_barrier(0);

  int s_cur = 0;
#pragma unroll 1
  for (int ph = 0; ph < CHUNKS_; ++ph) {
    const ushort_t* Ls = lds + s_cur * SLOT_E;
    bf16x8 af[4], bf[NBB];
#pragma unroll
    for (int mb = 0; mb < 4; ++mb)
      af[mb] = *(const bf16x8*)(Ls + rowA + mb * 512);
#pragma unroll
    for (int nb = 0; nb < NBB; ++nb)
      bf[nb] = *(const bf16x8*)(Ls + rowB + nb * 512);
    if (ph < CHUNKS_ - 2) {
      const int s_n2 = (s_cur == 0) ? 2 : s_cur - 1;  // (s_cur+2)%3
      STAGE_CHUNK(ph + 2, s_n2);
    }
    __builtin_amdgcn_s_setprio(1);
#pragma unroll
    for (int mb = 0; mb < 4; ++mb)
#pragma unroll
      for (int nb = 0; nb < NBB; ++nb)
        acc[mb][nb] = __builtin_amdgcn_mfma_f32_16x16x32_bf16(
            af[mb], bf[nb], acc[mb][nb], 0, 0, 0);
    __builtin_amdgcn_s_setprio(0);
    // counted drain: chunk ph+1 landed after this (never 0 until tail).
    if (ph < CHUNKS_ - 2) {
      if constexpr (BN == 256)
        asm volatile("s_waitcnt vmcnt(3)" ::: "memory");
      else
        asm volatile("s_waitcnt vmcnt(2)" ::: "memory");
    } else {
      asm volatile("s_waitcnt vmcnt(0)" ::: "memory");
    }
    __builtin_amdgcn_s_barrier();
    __builtin_amdgcn_sched_barrier(0);
    s_cur = (s_cur == 2) ? 0 : s_cur + 1;
  }

  float bb[NBB];
#pragma unroll
  for (int nb = 0; nb < NBB; ++nb)
    bb[nb] = bias[n0 + wc * WCOLS + nb * 16 + l15];

  if constexpr (WRITE_BF16) {
    // per-wave LDS patch [64][72] ushorts = 4608/wave; 8*4608 = 36864 fits.
    ushort_t* patch = lds + w * 4608;
    ushort_t* Cb = (ushort_t*)Cout;
#pragma unroll
    for (int mb = 0; mb < 4; ++mb)
#pragma unroll
      for (int nb = 0; nb < NBB; ++nb)
#pragma unroll
        for (int i = 0; i < 4; ++i)
          patch[(mb * 16 + quad * 4 + i) * 72 + nb * 16 + l15] =
              f2bf_fast(acc[mb][nb][i] + bb[nb]);
    // same-wave LDS write->read: ordered by lgkmcnt, no barrier needed.
#pragma unroll
    for (int it = 0; it < 8; ++it) {
      int rl = it * 8 + (lane >> 3);
      size_t grow = (size_t)(m0 + wr * 64 + rl);
      uint4 v = *(const uint4*)&patch[rl * 72 + (lane & 7) * 8];
      *(uint4*)&Cb[grow * N + n0 + wc * WCOLS + (lane & 7) * 8] = v;
    }
  } else {
    float* Cf = (float*)Cout;
#pragma unroll
    for (int mb = 0; mb < 4; ++mb)
#pragma unroll
      for (int i = 0; i < 4; ++i) {
        size_t row = (size_t)(m0 + wr * 64 + mb * 16 + quad * 4 + i);
#pragma unroll
        for (int nb = 0; nb < NBB; ++nb)
          Cf[row * N + n0 + wc * WCOLS + nb * 16 + l15] =
              acc[mb][nb][i] + bb[nb];
      }
  }
}

// ---------------------------------------------------------------------------
// MFMA flash attention, S^T formulation, software-pipelined.
// R8: 8 waves/block (512 thr), q-tile 256, grid (T/256,H,B)=512 blocks.
// Per-wave compute identical to R7 (32 q rows as 2 q-blocks of 16). K staging
// is now ONE gload/wave (8 rows x 8 waves); V staging done by tid<256 (same
// mapping as R7). Halves per-q staging/barrier cost and K/V refetch.
// LDS (37888 B, 2 blocks/CU by grid):
//   Kb0 @0 (8192) | Kb1 @8192 (8192) | Vb0 @16384 (8320) | Vb1 @24704 (8320)
//   bsh0 @33024 (256) | bsh1 @33280 (256) | lsum @36864 (1024)
//   Ost @0..36864 — epilogue only, aliases Kb/Vb (safe after final barrier)
// ---------------------------------------------------------------------------
#define ATTN_TILE(K0, Kc, Vc, bc, Kn, Vn, bn, PF)                              \
  {                                                                            \
    uint4 va_, vc_;                                                            \
    const bool pf_ = (PF);                                                     \
    if (pf_) {                                                                 \
      const int k1_ = (K0) + 64;                                               \
      gload_lds16(kbase + (size_t)(k1_ + w * 8 + kr8) * rs + kgc * 8,          \
                  &(Kn)[(w * 8) * 64]);                                        \
      if (tid < 256) {                                                         \
        const ushort_t* vp_ = vbase + (size_t)(k1_ + 2 * kp) * rs + cc * 8;    \
        va_ = *(const uint4*)vp_;                                              \
        vc_ = *(const uint4*)(vp_ + rs);                                       \
      }                                                                        \
      if (tid < 64) (bn)[tid] = bptr[k1_ + tid];                               \
    }                                                                          \
    bf16x8 kf0[4], kf1[4];                                                     \
    _Pragma("unroll")                                                          \
    for (int nb = 0; nb < 4; ++nb) {                                           \
      int key = nb * 16 + l15;                                                 \
      int p0 = (quad ^ (key & 7)) * 8;                                         \
      kf0[nb] = *(const bf16x8*)(&(Kc)[key * 64 + p0]);                        \
      kf1[nb] = *(const bf16x8*)(&(Kc)[key * 64 + (p0 ^ 32)]);                 \
    }                                                                          \
    bf16x8 vf0[4], vf1[4];                                                     \
    _Pragma("unroll")                                                          \
    for (int nbd = 0; nbd < 4; ++nbd) {                                        \
      vf0[nbd] = *(const bf16x8*)(&(Vc)[quad * 520 + (nbd * 16 + l15) * 8]);   \
      vf1[nbd] =                                                               \
          *(const bf16x8*)(&(Vc)[(4 + quad) * 520 + (nbd * 16 + l15) * 8]);    \
    }                                                                          \
    _Pragma("unroll")                                                          \
    for (int qb = 0; qb < 2; ++qb) {                                           \
      f32x4 st[4];                                                             \
      __builtin_amdgcn_s_setprio(1);                                           \
      _Pragma("unroll")                                                        \
      for (int nb = 0; nb < 4; ++nb) {                                         \
        f32x4 s = (f32x4){0.f, 0.f, 0.f, 0.f};                                 \
        s = __builtin_amdgcn_mfma_f32_16x16x32_bf16(kf0[nb], qf[qb][0], s, 0,  \
                                                    0, 0);                     \
        s = __builtin_amdgcn_mfma_f32_16x16x32_bf16(kf1[nb], qf[qb][1], s, 0,  \
                                                    0, 0);                     \
        st[nb] = s;                                                            \
      }                                                                        \
      __builtin_amdgcn_s_setprio(0);                                           \
      float pp[4][4];                                                          \
      float racc = 0.f;                                                        \
      _Pragma("unroll")                                                        \
      for (int nb = 0; nb < 4; ++nb) {                                         \
        f32x4 bv = *(const f32x4*)&(bc)[nb * 16 + quad * 4];                   \
        _Pragma("unroll")                                                      \
        for (int i = 0; i < 4; ++i) {                                          \
          float p = __builtin_amdgcn_exp2f(st[nb][i] * SC_LOG2 + bv[i]);       \
          pp[nb][i] = p;                                                       \
          racc += p;                                                           \
        }                                                                      \
      }                                                                        \
      rsum[qb] += racc;                                                        \
      union { uint4 u; bf16x8 v; } pf0, pf1;                                   \
      pf0.u.x = cvtpk_bf16(pp[0][0], pp[0][1]);                                \
      pf0.u.y = cvtpk_bf16(pp[0][2], pp[0][3]);                                \
      pf0.u.z = cvtpk_bf16(pp[1][0], pp[1][1]);                                \
      pf0.u.w = cvtpk_bf16(pp[1][2], pp[1][3]);                                \
      pf1.u.x = cvtpk_bf16(pp[2][0], pp[2][1]);                                \
      pf1.u.y = cvtpk_bf16(pp[2][2], pp[2][3]);                                \
      pf1.u.z = cvtpk_bf16(pp[3][0], pp[3][1]);                                \
      pf1.u.w = cvtpk_bf16(pp[3][2], pp[3][3]);                                \
      __builtin_amdgcn_s_setprio(1);                                           \
      _Pragma("unroll")                                                        \
      for (int nbd = 0; nbd < 4; ++nbd) {                                      \
        Oa[qb][nbd] = __builtin_amdgcn_mfma_f32_16x16x32_bf16(                 \
            pf0.v, vf0[nbd], Oa[qb][nbd], 0, 0, 0);                            \
        Oa[qb][nbd] = __builtin_amdgcn_mfma_f32_16x16x32_bf16(                 \
            pf1.v, vf1[nbd], Oa[qb][nbd], 0, 0, 0);                            \
      }                                                                        \
      __builtin_amdgcn_s_setprio(0);                                           \
    }                                                                          \
    if (pf_ && tid < 256) {                                                    \
      uint_t* dst_ = (uint_t*)&(Vn)[gp * 520 + cc * 64 + j0];                  \
      dst_[0]  = (va_.x & 0xffffu) | (vc_.x << 16);                            \
      dst_[4]  = (va_.x >> 16)     | (vc_.x & 0xffff0000u);                    \
      dst_[8]  = (va_.y & 0xffffu) | (vc_.y << 16);                            \
      dst_[12] = (va_.y >> 16)     | (vc_.y & 0xffff0000u);                    \
      dst_[16] = (va_.z & 0xffffu) | (vc_.z << 16);                            \
      dst_[20] = (va_.z >> 16)     | (vc_.z & 0xffff0000u);                    \
      dst_[24] = (va_.w & 0xffffu) | (vc_.w << 16);                            \
      dst_[28] = (va_.w >> 16)     | (vc_.w & 0xffff0000u);                    \
    }                                                                          \
    __syncthreads();                                                           \
  }

__global__ __launch_bounds__(512) void attn_mfma(
    const ushort_t* __restrict__ qkv, const float* __restrict__ biasA,
    ushort_t* __restrict__ oat) {
  __shared__ __align__(16) char smem[37888];
  ushort_t* Kb0 = (ushort_t*)(smem);
  ushort_t* Kb1 = (ushort_t*)(smem + 8192);
  ushort_t* Vb0 = (ushort_t*)(smem + 16384);
  ushort_t* Vb1 = (ushort_t*)(smem + 24704);
  float* bsh0 = (float*)(smem + 33024);
  float* bsh1 = (float*)(smem + 33280);
  float (*lsum)[32] = (float (*)[32])(smem + 36864);  // outside Ost region

  const int b = blockIdx.z, h = blockIdx.y;
  const int q0 = blockIdx.x * 256;
  const int tid = threadIdx.x;
  const int w = tid >> 6, lane = tid & 63;
  const int l15 = lane & 15, quad = lane >> 4;
  const size_t rs = 3 * D_;

  // Q B-frags (n=l15=q, k=quad*8+j=d) for the wave's 2 q-blocks.
  bf16x8 qf[2][2];
#pragma unroll
  for (int qb = 0; qb < 2; ++qb) {
    const ushort_t* qp =
        qkv + (size_t)(b * T_ + q0 + w * 32 + qb * 16 + l15) * rs + h * HD_;
    qf[qb][0] = *(const bf16x8*)(qp + quad * 8);
    qf[qb][1] = *(const bf16x8*)(qp + 32 + quad * 8);
  }

  f32x4 Oa[2][4];
#pragma unroll
  for (int qb = 0; qb < 2; ++qb)
#pragma unroll
    for (int nb = 0; nb < 4; ++nb) Oa[qb][nb] = (f32x4){0.f, 0.f, 0.f, 0.f};
  float rsum[2] = {0.f, 0.f};

  const ushort_t* kbase = qkv + (size_t)(b * T_) * rs + D_ + h * HD_;
  const ushort_t* vbase = kbase + D_;
  const float* bptr = biasA + b * T_;

  const int kr8 = lane >> 3;
  const int kgc = (lane & 7) ^ kr8;
  const int kp = tid & 31, cc = tid >> 5;  // V staging (tid<256 only: cc 0-7)
  const int gp = (kp >> 4) * 4 + ((kp >> 1) & 3);
  const int j0 = ((kp >> 3) & 1) * 4 + 2 * (kp & 1);

  // ---- prologue: stage tile 0 into buf0
  {
    gload_lds16(kbase + (size_t)(w * 8 + kr8) * rs + kgc * 8,
                &Kb0[(w * 8) * 64]);
    if (tid < 256) {
      const ushort_t* vp = vbase + (size_t)(2 * kp) * rs + cc * 8;
      uint4 va = *(const uint4*)vp;
      uint4 vc = *(const uint4*)(vp + rs);
      uint_t* dst = (uint_t*)&Vb0[gp * 520 + cc * 64 + j0];
      dst[0]  = (va.x & 0xffffu) | (vc.x << 16);
      dst[4]  = (va.x >> 16)     | (vc.x & 0xffff0000u);
      dst[8]  = (va.y & 0xffffu) | (vc.y << 16);
      dst[12] = (va.y >> 16)     | (vc.y & 0xffff0000u);
      dst[16] = (va.z & 0xffffu) | (vc.z << 16);
      dst[20] = (va.z >> 16)     | (vc.z & 0xffff0000u);
      dst[24] = (va.w & 0xffffu) | (vc.w << 16);
      dst[28] = (va.w >> 16)     | (vc.w & 0xffff0000u);
    }
    if (tid < 64) bsh0[tid] = bptr[tid];
  }
  __syncthreads();

  for (int k0 = 0; k0 < T_; k0 += 128) {
    ATTN_TILE(k0,      Kb0, Vb0, bsh0, Kb1, Vb1, bsh1, true);
    ATTN_TILE(k0 + 64, Kb1, Vb1, bsh1, Kb0, Vb0, bsh0, k0 + 128 < T_);
  }

  // ---- epilogue: rsum lives at q=l15; redistribute via per-wave LDS.
#pragma unroll
  for (int qb = 0; qb < 2; ++qb) {
    float r = rsum[qb];
    r += __shfl_xor(r, 16, 64);
    r += __shfl_xor(r, 32, 64);
    if (lane < 16) lsum[w][qb * 16 + lane] = r;
  }
  // Ost aliases Kb/Vb — safe: final tile ended with __syncthreads().
  ushort_t* OstW = (ushort_t*)(smem) + w * 2304;  // 32*72 ushorts per wave
  // same-wave LDS write->read: ordered by lgkmcnt, no barrier needed.
#pragma unroll
  for (int qb = 0; qb < 2; ++qb) {
    f32x4 lr = *(const f32x4*)&lsum[w][qb * 16 + quad * 4];
    f32x4 invl;
#pragma unroll
    for (int i = 0; i < 4; ++i) invl[i] = __builtin_amdgcn_rcpf(lr[i]);
#pragma unroll
    for (int nbd = 0; nbd < 4; ++nbd)
#pragma unroll
      for (int i = 0; i < 4; ++i)
        OstW[(qb * 16 + quad * 4 + i) * 72 + nbd * 16 + l15] =
            f2bf_fast(Oa[qb][nbd][i] * invl[i]);
  }
  ushort_t* dst = oat + (size_t)(b * T_ + q0 + w * 32) * D_ + h * HD_;
#pragma unroll
  for (int pp = 0; pp < 4; ++pp) {
    int row = pp * 8 + (lane >> 3), c = lane & 7;
    uint4 v = *(const uint4*)&OstW[row * 72 + c * 8];
    *(uint4*)&dst[(size_t)row * D_ + c * 8] = v;
  }
}

// ---------------------------------------------------------------------------
extern "C" void kernel_launch(void* const* d_in, const int* in_sizes, int n_in,
                              void* d_out, int out_size, void* d_ws, size_t ws_size,
                              hipStream_t stream) {
  const float* x     = (const float*)d_in[0];
  const float* eng   = (const float*)d_in[1];
  const int*   mask  = (const int*)d_in[2];
  const float* qkv_w = (const float*)d_in[3];
  const float* qkv_b = (const float*)d_in[4];
  const float* out_w = (const float*)d_in[5];
  const float* out_b = (const float*)d_in[6];
  float* out = (float*)d_out;

  const int M = B_ * T_;
  const size_t nx = (size_t)M * D_;
  const size_t nwq = (size_t)3 * D_ * D_;
  const size_t nwo = (size_t)D_ * D_;
  const size_t nqkv = (size_t)M * 3 * D_;

  char* p = (char*)d_ws;
  ushort_t* xb    = (ushort_t*)p;            p += nx * 2;
  ushort_t* wqkvb = (ushort_t*)p;            p += nwq * 2;
  ushort_t* woutb = (ushort_t*)p;            p += nwo * 2;
  ushort_t* qkvb  = (ushort_t*)p;            p += nqkv * 2;
  ushort_t* oatb  = (ushort_t*)p;            p += nx * 2;
  float*    biasA = (float*)p;               p += (size_t)M * 4;

  cvt_bf16<<<(int)(nx / 1024), 256, 0, stream>>>(x, xb, (int)nx);
  cvt_bf16<<<(int)(nwq / 1024), 256, 0, stream>>>(qkv_w, wqkvb, (int)nwq);
  cvt_bf16<<<(int)(nwo / 1024), 256, 0, stream>>>(out_w, woutb, (int)nwo);
  bias_prep<<<M / 256, 256, 0, stream>>>(eng, mask, biasA, M);

  // GEMM1: [8192,1024] @ [3072,1024]^T -> bf16 [8192,3072]; 64x12 = 768 blocks
  gemm256<1, 256><<<768, 512, 0, stream>>>(xb, wqkvb, qkv_b, qkvb, 3 * D_, 12);
  // attn: 512 thr, q-tile 256; grid 8*16*4 = 512 blocks
  attn_mfma<<<dim3(T_ / 256, H_, B_), 512, 0, stream>>>(qkvb, biasA, oatb);
  // GEMM2: [8192,1024] @ [1024,1024]^T -> f32 [8192,1024]; 64x8 = 512 blocks
  gemm256<0, 128><<<512, 512, 0, stream>>>(oatb, woutb, out_b, out, D_, 8);
}